// Round 1
// baseline (2364.908 us; speedup 1.0000x reference)
//
#include <hip/hip_runtime.h>
#include <hip/hip_bf16.h>

#define N_NODES 50000
#define N_EDGES 800000
#define D 128
#define N_ETYPES 4
#define N_STEPS 8
#define B_GRAPHS 50
#define HID 256

typedef __attribute__((ext_vector_type(8))) short short8;
typedef __attribute__((ext_vector_type(4))) float f32x4;

static __device__ __forceinline__ unsigned short f2bf(float f) {
    union { float f; unsigned u; } v; v.f = f;
    unsigned r = v.u + 0x7FFF + ((v.u >> 16) & 1);
    return (unsigned short)(r >> 16);
}
static __device__ __forceinline__ float bf2f(unsigned short s) {
    union { unsigned u; float f; } v; v.u = ((unsigned)s) << 16;
    return v.f;
}
static __device__ __forceinline__ float fsigmoid(float x) {
    return 1.f / (1.f + __expf(-x));
}
static __device__ __forceinline__ float ftanh(float x) {
    return 2.f / (1.f + __expf(-2.f * x)) - 1.f;
}

// ---------------- init: h_f32 = node_features, h_bf = bf16(h) ----------------
__global__ void k_init_h(const float* __restrict__ nf, float* __restrict__ hf,
                         unsigned short* __restrict__ hbf) {
    int i = blockIdx.x * blockDim.x + threadIdx.x;
    if (i < N_NODES * D) { float v = nf[i]; hf[i] = v; hbf[i] = f2bf(v); }
}

// ---------------- CSR build ----------------
__global__ void k_hist(const int* __restrict__ dst, int* __restrict__ deg) {
    int e = blockIdx.x * blockDim.x + threadIdx.x;
    if (e < N_EDGES) atomicAdd(&deg[dst[e]], 1);
}

__global__ void k_scan(const int* __restrict__ deg, int* __restrict__ rowptr,
                       int* __restrict__ cursor) {
    __shared__ int part[1024];
    int t = threadIdx.x;
    const int CH = (N_NODES + 1023) / 1024;  // 49
    int lo = t * CH;
    int hi = min(lo + CH, N_NODES);
    int s = 0;
    for (int i = lo; i < hi; ++i) s += deg[i];
    part[t] = s;
    __syncthreads();
    for (int off = 1; off < 1024; off <<= 1) {
        int v = (t >= off) ? part[t - off] : 0;
        __syncthreads();
        part[t] += v;
        __syncthreads();
    }
    int pfx = (t == 0) ? 0 : part[t - 1];
    for (int i = lo; i < hi; ++i) { rowptr[i] = pfx; cursor[i] = pfx; pfx += deg[i]; }
    if (t == 1023) rowptr[N_NODES] = pfx;  // = N_EDGES
}

__global__ void k_fill(const int* __restrict__ src, const int* __restrict__ dst,
                       const int* __restrict__ et, int* __restrict__ cursor,
                       int* __restrict__ epack) {
    int e = blockIdx.x * blockDim.x + threadIdx.x;
    if (e < N_EDGES) {
        int slot = atomicAdd(&cursor[dst[e]], 1);
        epack[slot] = src[e] | (et[e] << 16);  // src < 50000 < 2^16
    }
}

// ---------------- weight pre-pack into MFMA B-fragment layout (bf16) --------
// layout: ushort idx = ((ntile*4 + c)*64 + lane)*8 + i ; k = c*32 + (lane>>4)*8 + i
// msg: B[k][n] = Wmsg[n>>7][k][n&127], N=512 (32 ntiles)
// ih : B[k][n] = Wih[n][k],            N=384 (24 ntiles)
// hh : B[k][n] = Whh[n][k],            N=384 (24 ntiles)
__global__ void k_pack(const float* __restrict__ Wmsg, const float* __restrict__ Wih,
                       const float* __restrict__ Whh, unsigned short* __restrict__ Pmsg,
                       unsigned short* __restrict__ Pih, unsigned short* __restrict__ Phh) {
    int bt = blockIdx.x;  // 0..319
    int l = threadIdx.x;  // 0..63
    const float* src;
    unsigned short* dstp;
    int mode, nt, c;
    if (bt < 128)      { mode = 0; int id = bt;       nt = id >> 2; c = id & 3; src = Wmsg; dstp = Pmsg; }
    else if (bt < 224) { mode = 1; int id = bt - 128; nt = id >> 2; c = id & 3; src = Wih;  dstp = Pih;  }
    else               { mode = 2; int id = bt - 224; nt = id >> 2; c = id & 3; src = Whh;  dstp = Phh;  }
    int n = nt * 16 + (l & 15);
    int kb = l >> 4;
    unsigned short* out = dstp + (((nt * 4 + c) * 64 + l) * 8);
#pragma unroll
    for (int i = 0; i < 8; ++i) {
        int k = c * 32 + kb * 8 + i;
        float v;
        if (mode == 0) v = src[(n >> 7) * (D * D) + k * D + (n & 127)];
        else           v = src[n * D + k];
        out[i] = f2bf(v);
    }
}

// ---------------- message GEMM: M[v][0..511] = bf16(h[v] @ Wcat + bmsg) -----
__global__ __launch_bounds__(256) void k_gemm_msg(const unsigned short* __restrict__ hbf,
                                                  const unsigned short* __restrict__ Pmsg,
                                                  const float* __restrict__ bmsg,
                                                  unsigned short* __restrict__ M) {
    int w = threadIdx.x >> 6, l = threadIdx.x & 63;
    int base = blockIdx.x * 64 + w * 16;
    if (base >= N_NODES) return;
    int lr = l & 15, kb = l >> 4;
    const short8* arow = (const short8*)(hbf + (size_t)(base + lr) * D);
    short8 af[4];
#pragma unroll
    for (int c = 0; c < 4; ++c) af[c] = arow[c * 4 + kb];
#pragma unroll
    for (int pass = 0; pass < 4; ++pass) {
        f32x4 acc[8] = {};
#pragma unroll
        for (int c = 0; c < 4; ++c) {
#pragma unroll
            for (int t = 0; t < 8; ++t) {
                int ntile = pass * 8 + t;
                short8 bf = *(const short8*)(Pmsg + (((ntile * 4 + c) * 64 + l) * 8));
                acc[t] = __builtin_amdgcn_mfma_f32_16x16x32_bf16(af[c], bf, acc[t], 0, 0, 0);
            }
        }
        int row0 = base + kb * 4;  // C layout: row=(l>>4)*4+j, col=l&15 (m89)
#pragma unroll
        for (int t = 0; t < 8; ++t) {
            int col = (pass * 8 + t) * 16 + lr;
            float bias = bmsg[col];
#pragma unroll
            for (int j = 0; j < 4; ++j)
                M[(size_t)(row0 + j) * 512 + col] = f2bf(acc[t][j] + bias);
        }
    }
}

// ---------------- aggregate: a[v][d] = sum over in-edges of M[src][t*128+d] --
__global__ __launch_bounds__(256) void k_aggregate(const unsigned short* __restrict__ M,
                                                   const int* __restrict__ rowptr,
                                                   const int* __restrict__ epack,
                                                   unsigned short* __restrict__ abf) {
    int v = blockIdx.x * 2 + (threadIdx.x >> 7);
    int d = threadIdx.x & 127;
    int lo = rowptr[v], hi = rowptr[v + 1];
    float acc = 0.f;
    for (int i = lo; i < hi; ++i) {
        int ep = epack[i];
        int s = ep & 0xFFFF, t = ep >> 16;
        acc += bf2f(M[(size_t)s * 512 + t * 128 + d]);
    }
    abf[(size_t)v * D + d] = f2bf(acc);
}

// ---------------- fused GRU: gi = a@Wih^T, gh = h@Whh^T, gates, h update ----
__global__ __launch_bounds__(256) void k_gru(const unsigned short* __restrict__ abf,
                                             unsigned short* __restrict__ hbf,
                                             float* __restrict__ hf,
                                             const unsigned short* __restrict__ Pih,
                                             const unsigned short* __restrict__ Phh,
                                             const float* __restrict__ bih,
                                             const float* __restrict__ bhh) {
    int w = threadIdx.x >> 6, l = threadIdx.x & 63;
    int base = blockIdx.x * 64 + w * 16;
    if (base >= N_NODES) return;
    int lr = l & 15, kb = l >> 4;
    const short8* arow = (const short8*)(abf + (size_t)(base + lr) * D);
    const short8* hrow = (const short8*)(hbf + (size_t)(base + lr) * D);
    short8 afa[4], afh[4];
#pragma unroll
    for (int c = 0; c < 4; ++c) { afa[c] = arow[c * 4 + kb]; afh[c] = hrow[c * 4 + kb]; }
    float rr[8][4], zz[8][4];
#pragma unroll
    for (int p = 0; p < 3; ++p) {  // torch gate order: r, z, n
        f32x4 ai[8] = {}, ah[8] = {};
#pragma unroll
        for (int c = 0; c < 4; ++c) {
#pragma unroll
            for (int t = 0; t < 8; ++t) {
                int nt = p * 8 + t;
                short8 bi = *(const short8*)(Pih + (((nt * 4 + c) * 64 + l) * 8));
                ai[t] = __builtin_amdgcn_mfma_f32_16x16x32_bf16(afa[c], bi, ai[t], 0, 0, 0);
                short8 bh = *(const short8*)(Phh + (((nt * 4 + c) * 64 + l) * 8));
                ah[t] = __builtin_amdgcn_mfma_f32_16x16x32_bf16(afh[c], bh, ah[t], 0, 0, 0);
            }
        }
#pragma unroll
        for (int t = 0; t < 8; ++t) {
            int col = p * 128 + t * 16 + lr;
            float bi = bih[col], bh = bhh[col];
#pragma unroll
            for (int j = 0; j < 4; ++j) {
                float Gi = ai[t][j] + bi, Gh = ah[t][j] + bh;
                if (p == 0)      rr[t][j] = fsigmoid(Gi + Gh);
                else if (p == 1) zz[t][j] = fsigmoid(Gi + Gh);
                else {
                    float nn = ftanh(Gi + rr[t][j] * Gh);
                    int row = base + kb * 4 + j;
                    int dcol = t * 16 + lr;
                    size_t idx = (size_t)row * D + dcol;
                    float hold = hf[idx];
                    float hn = (1.f - zz[t][j]) * nn + zz[t][j] * hold;
                    hf[idx] = hn;
                    hbf[idx] = f2bf(hn);
                }
            }
        }
    }
}

// ---------------- pool + MLP + sigmoid ----------------
__global__ __launch_bounds__(256) void k_pool(const float* __restrict__ hf,
                                              const int* __restrict__ counts,
                                              const float* __restrict__ W1,
                                              const float* __restrict__ b1,
                                              const float* __restrict__ W2,
                                              const float* __restrict__ b2,
                                              float* __restrict__ out) {
    __shared__ float pooled[D];
    __shared__ float tmp[256];
    __shared__ float xh[HID];
    int g = blockIdx.x;
    int t = threadIdx.x;
    int offset = 0;
    for (int i = 0; i < g; ++i) offset += counts[i];
    int cnt = counts[g];
    int d = t & 127, half = t >> 7;
    float acc = 0.f;
    for (int r = half; r < cnt; r += 2) acc += hf[(size_t)(offset + r) * D + d];
    tmp[t] = acc;
    __syncthreads();
    if (t < D) pooled[t] = (tmp[t] + tmp[t + 128]) / (float)cnt;
    __syncthreads();
    float x = b1[t];
    for (int k = 0; k < D; ++k) x += pooled[k] * W1[k * HID + t];
    x = fmaxf(x, 0.f);
    xh[t] = x * W2[t];
    __syncthreads();
    for (int s = 128; s > 0; s >>= 1) {
        if (t < s) xh[t] += xh[t + s];
        __syncthreads();
    }
    if (t == 0) out[g] = 1.f / (1.f + __expf(-(xh[0] + b2[0])));
}

extern "C" void kernel_launch(void* const* d_in, const int* in_sizes, int n_in,
                              void* d_out, int out_size, void* d_ws, size_t ws_size,
                              hipStream_t stream) {
    const float* nf   = (const float*)d_in[0];
    const int* esrc   = (const int*)d_in[1];
    const int* edst   = (const int*)d_in[2];
    const int* etyp   = (const int*)d_in[3];
    const int* counts = (const int*)d_in[4];
    const float* Wmsg = (const float*)d_in[5];
    const float* bmsg = (const float*)d_in[6];   // [4][128] flat == [512] concat
    const float* Wih  = (const float*)d_in[7];
    const float* Whh  = (const float*)d_in[8];
    const float* bih  = (const float*)d_in[9];
    const float* bhh  = (const float*)d_in[10];
    const float* W1   = (const float*)d_in[11];
    const float* b1   = (const float*)d_in[12];
    const float* W2   = (const float*)d_in[13];
    const float* b2   = (const float*)d_in[14];
    float* out = (float*)d_out;

    char* ws = (char*)d_ws;
    size_t off = 0;
    auto alloc = [&](size_t bytes) {
        void* p = ws + off;
        off = (off + bytes + 255) & ~(size_t)255;
        return p;
    };
    float* hf            = (float*)alloc((size_t)N_NODES * D * 4);
    unsigned short* hbf  = (unsigned short*)alloc((size_t)N_NODES * D * 2);
    unsigned short* abf  = (unsigned short*)alloc((size_t)N_NODES * D * 2);
    unsigned short* M    = (unsigned short*)alloc((size_t)N_NODES * 512 * 2);
    unsigned short* Pmsg = (unsigned short*)alloc(32 * 4 * 64 * 8 * 2);
    unsigned short* Pih  = (unsigned short*)alloc(24 * 4 * 64 * 8 * 2);
    unsigned short* Phh  = (unsigned short*)alloc(24 * 4 * 64 * 8 * 2);
    int* deg    = (int*)alloc((size_t)N_NODES * 4);
    int* rowptr = (int*)alloc((size_t)(N_NODES + 1) * 4);
    int* cursor = (int*)alloc((size_t)N_NODES * 4);
    int* epack  = (int*)alloc((size_t)N_EDGES * 4);

    hipMemsetAsync(deg, 0, (size_t)N_NODES * 4, stream);
    k_init_h<<<(N_NODES * D) / 256, 256, 0, stream>>>(nf, hf, hbf);
    k_hist<<<N_EDGES / 256, 256, 0, stream>>>(edst, deg);
    k_scan<<<1, 1024, 0, stream>>>(deg, rowptr, cursor);
    k_fill<<<N_EDGES / 256, 256, 0, stream>>>(esrc, edst, etyp, cursor, epack);
    k_pack<<<320, 64, 0, stream>>>(Wmsg, Wih, Whh, Pmsg, Pih, Phh);

    int gblocks = (N_NODES + 63) / 64;  // 782
    for (int s = 0; s < N_STEPS; ++s) {
        k_gemm_msg<<<gblocks, 256, 0, stream>>>(hbf, Pmsg, bmsg, M);
        k_aggregate<<<N_NODES / 2, 256, 0, stream>>>(M, rowptr, epack, abf);
        k_gru<<<gblocks, 256, 0, stream>>>(abf, hbf, hf, Pih, Phh, bih, bhh);
    }
    k_pool<<<B_GRAPHS, 256, 0, stream>>>(hf, counts, W1, b1, W2, b2, out);
}

// Round 2
// 1447.196 us; speedup vs baseline: 1.6341x; 1.6341x over previous
//
#include <hip/hip_runtime.h>
#include <hip/hip_bf16.h>

#define N_NODES 50000
#define N_EDGES 800000
#define D 128
#define N_ETYPES 4
#define N_STEPS 8
#define B_GRAPHS 50
#define HID 256
#define POOL_SPLIT 16

typedef __attribute__((ext_vector_type(8))) short short8;
typedef __attribute__((ext_vector_type(4))) float f32x4;

static __device__ __forceinline__ unsigned short f2bf(float f) {
    union { float f; unsigned u; } v; v.f = f;
    unsigned r = v.u + 0x7FFF + ((v.u >> 16) & 1);
    return (unsigned short)(r >> 16);
}
static __device__ __forceinline__ float bf2f_u(unsigned s) {  // low 16 bits
    union { unsigned u; float f; } v; v.u = s << 16;
    return v.f;
}
static __device__ __forceinline__ float fsigmoid(float x) {
    return 1.f / (1.f + __expf(-x));
}
static __device__ __forceinline__ float ftanh(float x) {
    return 2.f / (1.f + __expf(-2.f * x)) - 1.f;
}
static __device__ __forceinline__ void gload_lds16(const void* g, void* lds) {
    __builtin_amdgcn_global_load_lds(
        (const __attribute__((address_space(1))) unsigned char*)g,
        (__attribute__((address_space(3))) unsigned char*)lds, 16, 0, 0);
}

// ---------------- init: h_f32 = node_features, h_bf = bf16(h) ----------------
__global__ void k_init_h(const float* __restrict__ nf, float* __restrict__ hf,
                         unsigned short* __restrict__ hbf) {
    int i = blockIdx.x * blockDim.x + threadIdx.x;
    if (i < N_NODES * D) { float v = nf[i]; hf[i] = v; hbf[i] = f2bf(v); }
}

// ---------------- CSR build ----------------
__global__ void k_hist(const int* __restrict__ dst, int* __restrict__ deg) {
    int e = blockIdx.x * blockDim.x + threadIdx.x;
    if (e < N_EDGES) atomicAdd(&deg[dst[e]], 1);
}

__global__ void k_scan(const int* __restrict__ deg, int* __restrict__ rowptr,
                       int* __restrict__ cursor) {
    __shared__ int part[1024];
    int t = threadIdx.x;
    const int CH = (N_NODES + 1023) / 1024;  // 49
    int lo = t * CH;
    int hi = min(lo + CH, N_NODES);
    int s = 0;
    for (int i = lo; i < hi; ++i) s += deg[i];
    part[t] = s;
    __syncthreads();
    for (int off = 1; off < 1024; off <<= 1) {
        int v = (t >= off) ? part[t - off] : 0;
        __syncthreads();
        part[t] += v;
        __syncthreads();
    }
    int pfx = (t == 0) ? 0 : part[t - 1];
    for (int i = lo; i < hi; ++i) { rowptr[i] = pfx; cursor[i] = pfx; pfx += deg[i]; }
    if (t == 1023) rowptr[N_NODES] = pfx;  // = N_EDGES
}

__global__ void k_fill(const int* __restrict__ src, const int* __restrict__ dst,
                       const int* __restrict__ et, int* __restrict__ cursor,
                       int* __restrict__ epack) {
    int e = blockIdx.x * blockDim.x + threadIdx.x;
    if (e < N_EDGES) {
        int slot = atomicAdd(&cursor[dst[e]], 1);
        epack[slot] = src[e] | (et[e] << 16);  // src < 50000 < 2^16
    }
}

// ---------------- weight pre-pack into MFMA B-fragment layout (bf16) --------
// frag f = ntile*4 + c ; ushort idx = (f*64 + lane)*8 + i ; k = c*32 + (lane>>4)*8 + i
__global__ void k_pack(const float* __restrict__ Wmsg, const float* __restrict__ Wih,
                       const float* __restrict__ Whh, unsigned short* __restrict__ Pmsg,
                       unsigned short* __restrict__ Pih, unsigned short* __restrict__ Phh) {
    int bt = blockIdx.x;  // 0..319
    int l = threadIdx.x;  // 0..63
    const float* src;
    unsigned short* dstp;
    int mode, nt, c;
    if (bt < 128)      { mode = 0; int id = bt;       nt = id >> 2; c = id & 3; src = Wmsg; dstp = Pmsg; }
    else if (bt < 224) { mode = 1; int id = bt - 128; nt = id >> 2; c = id & 3; src = Wih;  dstp = Pih;  }
    else               { mode = 2; int id = bt - 224; nt = id >> 2; c = id & 3; src = Whh;  dstp = Phh;  }
    int n = nt * 16 + (l & 15);
    int kb = l >> 4;
    unsigned short* out = dstp + (((nt * 4 + c) * 64 + l) * 8);
#pragma unroll
    for (int i = 0; i < 8; ++i) {
        int k = c * 32 + kb * 8 + i;
        float v;
        if (mode == 0) v = src[(n >> 7) * (D * D) + k * D + (n & 127)];
        else           v = src[n * D + k];
        out[i] = f2bf(v);
    }
}

// ---------------- message GEMM: M[v][0..511] = bf16(h[v] @ Wcat + bmsg) -----
// block: 256 thr = 4 waves, each wave owns 32 rows (2 rowgroups), block 128 rows
// per pass p (4): stage frags [p*32, p*32+32) (32 KB) in LDS, shared by all waves
__global__ __launch_bounds__(256) void k_gemm_msg(const unsigned short* __restrict__ hbf,
                                                  const unsigned short* __restrict__ Pmsg,
                                                  const float* __restrict__ bmsg,
                                                  unsigned short* __restrict__ M) {
    __shared__ unsigned short Bs[32 * 64 * 8];  // 32 KB
    int tid = threadIdx.x, w = tid >> 6, l = tid & 63;
    int base = blockIdx.x * 128 + w * 32;
    int lr = l & 15, kb = l >> 4;
    short8 af[2][4];
#pragma unroll
    for (int r = 0; r < 2; ++r) {
        int row = base + r * 16 + lr;
        if (row >= N_NODES) row = N_NODES - 1;
        const short8* arow = (const short8*)(hbf + (size_t)row * D);
#pragma unroll
        for (int c = 0; c < 4; ++c) af[r][c] = arow[c * 4 + kb];
    }
    for (int p = 0; p < 4; ++p) {
        __syncthreads();  // protect Bs from previous pass readers
#pragma unroll
        for (int j = 0; j < 8; ++j) {
            int ci = j * 4 + w;  // chunk 0..31, one 1 KB frag per wave
            gload_lds16(Pmsg + ((size_t)(p * 32 + ci) * 64 + l) * 8, Bs + (size_t)ci * 512);
        }
        __syncthreads();
        f32x4 acc[2][8] = {};
#pragma unroll
        for (int c = 0; c < 4; ++c) {
#pragma unroll
            for (int t = 0; t < 8; ++t) {
                short8 bf = *(const short8*)(Bs + ((t * 4 + c) * 64 + l) * 8);
                acc[0][t] = __builtin_amdgcn_mfma_f32_16x16x32_bf16(af[0][c], bf, acc[0][t], 0, 0, 0);
                acc[1][t] = __builtin_amdgcn_mfma_f32_16x16x32_bf16(af[1][c], bf, acc[1][t], 0, 0, 0);
            }
        }
#pragma unroll
        for (int t = 0; t < 8; ++t) {
            int col = (p * 8 + t) * 16 + lr;
            float bias = bmsg[col];
#pragma unroll
            for (int r = 0; r < 2; ++r) {
                int row0 = base + r * 16 + kb * 4;
#pragma unroll
                for (int j = 0; j < 4; ++j) {
                    int row = row0 + j;
                    if (row < N_NODES)
                        M[(size_t)row * 512 + col] = f2bf(acc[r][t][j] + bias);
                }
            }
        }
    }
}

// ---------------- aggregate: a[v][d] = sum over in-edges of M[src][t*128+d] --
// one wave per node; lane l covers d=2l,2l+1; unroll-4 independent loads
__global__ __launch_bounds__(256) void k_aggregate(const unsigned short* __restrict__ M,
                                                   const int* __restrict__ rowptr,
                                                   const int* __restrict__ epack,
                                                   unsigned short* __restrict__ abf) {
    int w = threadIdx.x >> 6, l = threadIdx.x & 63;
    int v = blockIdx.x * 4 + w;
    if (v >= N_NODES) return;
    int lo = rowptr[v], hi = rowptr[v + 1];
    float a0 = 0.f, a1 = 0.f;
    int i = lo;
    for (; i + 4 <= hi; i += 4) {
        int e0 = epack[i], e1 = epack[i + 1], e2 = epack[i + 2], e3 = epack[i + 3];
        unsigned x0 = *(const unsigned*)(M + ((size_t)(e0 & 0xFFFF) << 9) + ((e0 >> 16) << 7) + 2 * l);
        unsigned x1 = *(const unsigned*)(M + ((size_t)(e1 & 0xFFFF) << 9) + ((e1 >> 16) << 7) + 2 * l);
        unsigned x2 = *(const unsigned*)(M + ((size_t)(e2 & 0xFFFF) << 9) + ((e2 >> 16) << 7) + 2 * l);
        unsigned x3 = *(const unsigned*)(M + ((size_t)(e3 & 0xFFFF) << 9) + ((e3 >> 16) << 7) + 2 * l);
        a0 += bf2f_u(x0 & 0xFFFF) + bf2f_u(x1 & 0xFFFF) + bf2f_u(x2 & 0xFFFF) + bf2f_u(x3 & 0xFFFF);
        a1 += bf2f_u(x0 >> 16) + bf2f_u(x1 >> 16) + bf2f_u(x2 >> 16) + bf2f_u(x3 >> 16);
    }
    for (; i < hi; ++i) {
        int e0 = epack[i];
        unsigned x0 = *(const unsigned*)(M + ((size_t)(e0 & 0xFFFF) << 9) + ((e0 >> 16) << 7) + 2 * l);
        a0 += bf2f_u(x0 & 0xFFFF);
        a1 += bf2f_u(x0 >> 16);
    }
    abf[(size_t)v * D + 2 * l] = f2bf(a0);
    abf[(size_t)v * D + 2 * l + 1] = f2bf(a1);
}

// ---------------- fused GRU: gi = a@Wih^T, gh = h@Whh^T, gates, h update ----
// block 64 rows (4 waves x 16); per (p,hp): stage 4 ih-frag-tiles + 4 hh (32 KB)
__global__ __launch_bounds__(256) void k_gru(const unsigned short* __restrict__ abf,
                                             unsigned short* __restrict__ hbf,
                                             float* __restrict__ hf,
                                             const unsigned short* __restrict__ Pih,
                                             const unsigned short* __restrict__ Phh,
                                             const float* __restrict__ bih,
                                             const float* __restrict__ bhh) {
    __shared__ unsigned short Bs[32 * 64 * 8];  // 32 KB: [0..15]=ih frags, [16..31]=hh frags
    int tid = threadIdx.x, w = tid >> 6, l = tid & 63;
    int base = blockIdx.x * 64 + w * 16;
    int lr = l & 15, kb = l >> 4;
    int arow_i = base + lr;
    if (arow_i >= N_NODES) arow_i = N_NODES - 1;
    const short8* arow = (const short8*)(abf + (size_t)arow_i * D);
    const short8* hrow = (const short8*)(hbf + (size_t)arow_i * D);
    short8 afa[4], afh[4];
#pragma unroll
    for (int c = 0; c < 4; ++c) { afa[c] = arow[c * 4 + kb]; afh[c] = hrow[c * 4 + kb]; }
    float rr[8][4], zz[8][4];
    for (int p = 0; p < 3; ++p) {
        for (int hp = 0; hp < 2; ++hp) {
            __syncthreads();
#pragma unroll
            for (int j = 0; j < 8; ++j) {
                int ci = j * 4 + w;  // 0..31
                int fl = ci & 15;    // local frag: (nt_local*4 + c), nt_local 0..3
                const unsigned short* src = (ci < 16) ? Pih : Phh;
                size_t gfrag = (size_t)((p * 8 + hp * 4) * 4 + fl);  // (nt_global*4+c)
                gload_lds16(src + (gfrag * 64 + l) * 8, Bs + (size_t)ci * 512);
            }
            __syncthreads();
            f32x4 ai[4] = {}, ah[4] = {};
#pragma unroll
            for (int c = 0; c < 4; ++c) {
#pragma unroll
                for (int tl = 0; tl < 4; ++tl) {
                    short8 bi = *(const short8*)(Bs + ((tl * 4 + c) * 64 + l) * 8);
                    ai[tl] = __builtin_amdgcn_mfma_f32_16x16x32_bf16(afa[c], bi, ai[tl], 0, 0, 0);
                    short8 bh = *(const short8*)(Bs + ((16 + tl * 4 + c) * 64 + l) * 8);
                    ah[tl] = __builtin_amdgcn_mfma_f32_16x16x32_bf16(afh[c], bh, ah[tl], 0, 0, 0);
                }
            }
#pragma unroll
            for (int tl = 0; tl < 4; ++tl) {
                int t = hp * 4 + tl;
                int col = p * 128 + t * 16 + lr;
                float bi = bih[col], bh = bhh[col];
#pragma unroll
                for (int j = 0; j < 4; ++j) {
                    float Gi = ai[tl][j] + bi, Gh = ah[tl][j] + bh;
                    if (p == 0)      rr[t][j] = fsigmoid(Gi + Gh);
                    else if (p == 1) zz[t][j] = fsigmoid(Gi + Gh);
                    else {
                        float nn = ftanh(Gi + rr[t][j] * Gh);
                        int row = base + kb * 4 + j;
                        if (row < N_NODES) {
                            int dcol = t * 16 + lr;
                            size_t idx = (size_t)row * D + dcol;
                            float hold = hf[idx];
                            float hn = (1.f - zz[t][j]) * nn + zz[t][j] * hold;
                            hf[idx] = hn;
                            hbf[idx] = f2bf(hn);
                        }
                    }
                }
            }
        }
    }
}

// ---------------- pool phase 1: partial row-sums ----------------
__global__ __launch_bounds__(256) void k_pool1(const float* __restrict__ hf,
                                               const int* __restrict__ counts,
                                               float* __restrict__ partial) {
    __shared__ float tmp[256];
    int g = blockIdx.x / POOL_SPLIT;
    int j = blockIdx.x % POOL_SPLIT;
    int t = threadIdx.x;
    int offset = 0;
    for (int i = 0; i < g; ++i) offset += counts[i];
    int cnt = counts[g];
    int d = t & 127, half = t >> 7;
    float acc = 0.f;
    for (int r = 2 * j + half; r < cnt; r += 2 * POOL_SPLIT)
        acc += hf[(size_t)(offset + r) * D + d];
    tmp[t] = acc;
    __syncthreads();
    if (t < D) partial[(size_t)(g * POOL_SPLIT + j) * D + t] = tmp[t] + tmp[t + 128];
}

// ---------------- pool phase 2: combine + MLP + sigmoid ----------------
__global__ __launch_bounds__(256) void k_pool2(const float* __restrict__ partial,
                                               const int* __restrict__ counts,
                                               const float* __restrict__ W1,
                                               const float* __restrict__ b1,
                                               const float* __restrict__ W2,
                                               const float* __restrict__ b2,
                                               float* __restrict__ out) {
    __shared__ float pooled[D];
    __shared__ float xh[HID];
    int g = blockIdx.x;
    int t = threadIdx.x;
    int cnt = counts[g];
    if (t < D) {
        float s = 0.f;
#pragma unroll
        for (int j = 0; j < POOL_SPLIT; ++j)
            s += partial[(size_t)(g * POOL_SPLIT + j) * D + t];
        pooled[t] = s / (float)cnt;
    }
    __syncthreads();
    float x = b1[t];
    for (int k = 0; k < D; ++k) x += pooled[k] * W1[k * HID + t];
    x = fmaxf(x, 0.f);
    xh[t] = x * W2[t];
    __syncthreads();
    for (int s = 128; s > 0; s >>= 1) {
        if (t < s) xh[t] += xh[t + s];
        __syncthreads();
    }
    if (t == 0) out[g] = 1.f / (1.f + __expf(-(xh[0] + b2[0])));
}

extern "C" void kernel_launch(void* const* d_in, const int* in_sizes, int n_in,
                              void* d_out, int out_size, void* d_ws, size_t ws_size,
                              hipStream_t stream) {
    const float* nf   = (const float*)d_in[0];
    const int* esrc   = (const int*)d_in[1];
    const int* edst   = (const int*)d_in[2];
    const int* etyp   = (const int*)d_in[3];
    const int* counts = (const int*)d_in[4];
    const float* Wmsg = (const float*)d_in[5];
    const float* bmsg = (const float*)d_in[6];   // [4][128] flat == [512] concat
    const float* Wih  = (const float*)d_in[7];
    const float* Whh  = (const float*)d_in[8];
    const float* bih  = (const float*)d_in[9];
    const float* bhh  = (const float*)d_in[10];
    const float* W1   = (const float*)d_in[11];
    const float* b1   = (const float*)d_in[12];
    const float* W2   = (const float*)d_in[13];
    const float* b2   = (const float*)d_in[14];
    float* out = (float*)d_out;

    char* ws = (char*)d_ws;
    size_t off = 0;
    auto alloc = [&](size_t bytes) {
        void* p = ws + off;
        off = (off + bytes + 255) & ~(size_t)255;
        return p;
    };
    float* hf            = (float*)alloc((size_t)N_NODES * D * 4);
    unsigned short* hbf  = (unsigned short*)alloc((size_t)N_NODES * D * 2);
    unsigned short* abf  = (unsigned short*)alloc((size_t)N_NODES * D * 2);
    unsigned short* M    = (unsigned short*)alloc((size_t)N_NODES * 512 * 2);
    unsigned short* Pmsg = (unsigned short*)alloc(32 * 4 * 64 * 8 * 2);
    unsigned short* Pih  = (unsigned short*)alloc(24 * 4 * 64 * 8 * 2);
    unsigned short* Phh  = (unsigned short*)alloc(24 * 4 * 64 * 8 * 2);
    int* deg    = (int*)alloc((size_t)N_NODES * 4);
    int* rowptr = (int*)alloc((size_t)(N_NODES + 1) * 4);
    int* cursor = (int*)alloc((size_t)N_NODES * 4);
    int* epack  = (int*)alloc((size_t)N_EDGES * 4);
    float* partial = (float*)alloc((size_t)B_GRAPHS * POOL_SPLIT * D * 4);

    hipMemsetAsync(deg, 0, (size_t)N_NODES * 4, stream);
    k_init_h<<<(N_NODES * D) / 256, 256, 0, stream>>>(nf, hf, hbf);
    k_hist<<<N_EDGES / 256, 256, 0, stream>>>(edst, deg);
    k_scan<<<1, 1024, 0, stream>>>(deg, rowptr, cursor);
    k_fill<<<N_EDGES / 256, 256, 0, stream>>>(esrc, edst, etyp, cursor, epack);
    k_pack<<<320, 64, 0, stream>>>(Wmsg, Wih, Whh, Pmsg, Pih, Phh);

    int msg_blocks = (N_NODES + 127) / 128;  // 391
    int gru_blocks = (N_NODES + 63) / 64;    // 782
    int agg_blocks = (N_NODES + 3) / 4;      // 12500
    for (int s = 0; s < N_STEPS; ++s) {
        k_gemm_msg<<<msg_blocks, 256, 0, stream>>>(hbf, Pmsg, bmsg, M);
        k_aggregate<<<agg_blocks, 256, 0, stream>>>(M, rowptr, epack, abf);
        k_gru<<<gru_blocks, 256, 0, stream>>>(abf, hbf, hf, Pih, Phh, bih, bhh);
    }
    k_pool1<<<B_GRAPHS * POOL_SPLIT, 256, 0, stream>>>(hf, counts, partial);
    k_pool2<<<B_GRAPHS, 256, 0, stream>>>(partial, counts, W1, b1, W2, b2, out);
}

// Round 3
// 1312.520 us; speedup vs baseline: 1.8018x; 1.1026x over previous
//
#include <hip/hip_runtime.h>
#include <hip/hip_bf16.h>

#define N_NODES 50000
#define N_EDGES 800000
#define D 128
#define N_ETYPES 4
#define N_STEPS 8
#define B_GRAPHS 50
#define HID 256
#define POOL_SPLIT 16
#define SCAN_B 196  // ceil(50000/256)

typedef __attribute__((ext_vector_type(8))) short short8;
typedef __attribute__((ext_vector_type(4))) float f32x4;
typedef __attribute__((ext_vector_type(4))) unsigned uint4v;

static __device__ __forceinline__ unsigned short f2bf(float f) {
    union { float f; unsigned u; } v; v.f = f;
    unsigned r = v.u + 0x7FFF + ((v.u >> 16) & 1);
    return (unsigned short)(r >> 16);
}
static __device__ __forceinline__ float bf2f_u(unsigned s) {  // low 16 bits
    union { unsigned u; float f; } v; v.u = s << 16;
    return v.f;
}
static __device__ __forceinline__ float fsigmoid(float x) {
    return 1.f / (1.f + __expf(-x));
}
static __device__ __forceinline__ float ftanh(float x) {
    return 2.f / (1.f + __expf(-2.f * x)) - 1.f;
}
static __device__ __forceinline__ void gload_lds16(const void* g, void* lds) {
    __builtin_amdgcn_global_load_lds(
        (const __attribute__((address_space(1))) unsigned char*)g,
        (__attribute__((address_space(3))) unsigned char*)lds, 16, 0, 0);
}

// ---------------- init: h_f32 = node_features, h_bf = bf16(h) ----------------
__global__ void k_init_h(const float* __restrict__ nf, float* __restrict__ hf,
                         unsigned short* __restrict__ hbf) {
    int i = blockIdx.x * blockDim.x + threadIdx.x;
    if (i < N_NODES * D) { float v = nf[i]; hf[i] = v; hbf[i] = f2bf(v); }
}

// ---------------- CSR build ----------------
__global__ void k_hist(const int* __restrict__ dst, int* __restrict__ deg) {
    int e = blockIdx.x * blockDim.x + threadIdx.x;
    if (e < N_EDGES) atomicAdd(&deg[dst[e]], 1);
}

// phase 1: per-block sums
__global__ __launch_bounds__(256) void k_scan1(const int* __restrict__ deg,
                                               int* __restrict__ bsum) {
    __shared__ int tmp[256];
    int t = threadIdx.x;
    int i = blockIdx.x * 256 + t;
    tmp[t] = (i < N_NODES) ? deg[i] : 0;
    __syncthreads();
    for (int s = 128; s > 0; s >>= 1) {
        if (t < s) tmp[t] += tmp[t + s];
        __syncthreads();
    }
    if (t == 0) bsum[blockIdx.x] = tmp[0];
}

// phase 2: exclusive scan of block sums (SCAN_B <= 256)
__global__ __launch_bounds__(256) void k_scan2(const int* __restrict__ bsum,
                                               int* __restrict__ bpfx,
                                               int* __restrict__ rowptr) {
    __shared__ int part[256];
    int t = threadIdx.x;
    int v = (t < SCAN_B) ? bsum[t] : 0;
    part[t] = v;
    __syncthreads();
    for (int off = 1; off < 256; off <<= 1) {
        int u = (t >= off) ? part[t - off] : 0;
        __syncthreads();
        part[t] += u;
        __syncthreads();
    }
    if (t < SCAN_B) bpfx[t] = part[t] - v;  // exclusive
    if (t == SCAN_B - 1) rowptr[N_NODES] = part[t];
}

// phase 3: block-local exclusive scan + base
__global__ __launch_bounds__(256) void k_scan3(const int* __restrict__ deg,
                                               const int* __restrict__ bpfx,
                                               int* __restrict__ rowptr,
                                               int* __restrict__ cursor) {
    __shared__ int part[256];
    int t = threadIdx.x;
    int i = blockIdx.x * 256 + t;
    int v = (i < N_NODES) ? deg[i] : 0;
    part[t] = v;
    __syncthreads();
    for (int off = 1; off < 256; off <<= 1) {
        int u = (t >= off) ? part[t - off] : 0;
        __syncthreads();
        part[t] += u;
        __syncthreads();
    }
    if (i < N_NODES) {
        int rp = bpfx[blockIdx.x] + part[t] - v;
        rowptr[i] = rp;
        cursor[i] = rp;
    }
}

__global__ void k_fill(const int* __restrict__ src, const int* __restrict__ dst,
                       const int* __restrict__ et, int* __restrict__ cursor,
                       int* __restrict__ epack) {
    int e = blockIdx.x * blockDim.x + threadIdx.x;
    if (e < N_EDGES) {
        int slot = atomicAdd(&cursor[dst[e]], 1);
        epack[slot] = src[e] | (et[e] << 16);  // src < 50000 < 2^16
    }
}

// ---------------- weight pre-pack into MFMA B-fragment layouts (bf16) --------
// Pmsg (Wstack, K=512, N=128): frag f = nt*16 + kc (nt<8, kc<16);
//   idx = (f*64 + l)*8 + i ; k = kc*32 + (l>>4)*8 + i ; n = nt*16 + (l&15)
//   Wstack[k][n] = Wmsg[k>>7][(k&127)*128 + n]
// Pih/Phh (K=128, N=384): frag f = nt*4 + c ; k = c*32 + (l>>4)*8 + i ; B[k][n]=W[n][k]
__global__ void k_pack(const float* __restrict__ Wmsg, const float* __restrict__ Wih,
                       const float* __restrict__ Whh, unsigned short* __restrict__ Pmsg,
                       unsigned short* __restrict__ Pih, unsigned short* __restrict__ Phh) {
    int bt = blockIdx.x;  // 0..319
    int l = threadIdx.x;  // 0..63
    if (bt < 128) {  // Pmsg frag f = bt
        int nt = bt >> 4, kc = bt & 15;
        int n = nt * 16 + (l & 15);
        unsigned short* out = Pmsg + (((size_t)bt * 64 + l) * 8);
#pragma unroll
        for (int i = 0; i < 8; ++i) {
            int k = kc * 32 + ((l >> 4) << 3) + i;
            out[i] = f2bf(Wmsg[(size_t)(k >> 7) * (D * D) + (k & 127) * D + n]);
        }
        return;
    }
    const float* src;
    unsigned short* dstp;
    int id;
    if (bt < 224) { id = bt - 128; src = Wih; dstp = Pih; }
    else          { id = bt - 224; src = Whh; dstp = Phh; }
    int nt = id >> 2, c = id & 3;
    int n = nt * 16 + (l & 15);
    unsigned short* out = dstp + (((size_t)(nt * 4 + c) * 64 + l) * 8);
#pragma unroll
    for (int i = 0; i < 8; ++i) {
        int k = c * 32 + ((l >> 4) << 3) + i;
        out[i] = f2bf(src[n * D + k]);
    }
}

// ---------------- aggregate: S[v][t][d] = sum_{in-edges of type t} hbf[src][d] --
// one wave per node; lane l covers d=2l,2l+1; also writes deg4[v][t]
__global__ __launch_bounds__(256) void k_aggregate_s(const unsigned short* __restrict__ hbf,
                                                     const int* __restrict__ rowptr,
                                                     const int* __restrict__ epack,
                                                     unsigned short* __restrict__ S,
                                                     unsigned* __restrict__ deg4) {
    int w = threadIdx.x >> 6, l = threadIdx.x & 63;
    int v = blockIdx.x * 4 + w;
    if (v >= N_NODES) return;
    int lo = rowptr[v], hi = rowptr[v + 1];
    float a00 = 0.f, a01 = 0.f, a10 = 0.f, a11 = 0.f;
    float a20 = 0.f, a21 = 0.f, a30 = 0.f, a31 = 0.f;
    unsigned c0 = 0, c1 = 0, c2 = 0, c3 = 0;
    int i = lo;
    for (; i + 4 <= hi; i += 4) {
        int e0 = epack[i], e1 = epack[i + 1], e2 = epack[i + 2], e3 = epack[i + 3];
        unsigned x0 = *(const unsigned*)(hbf + ((size_t)(e0 & 0xFFFF) << 7) + 2 * l);
        unsigned x1 = *(const unsigned*)(hbf + ((size_t)(e1 & 0xFFFF) << 7) + 2 * l);
        unsigned x2 = *(const unsigned*)(hbf + ((size_t)(e2 & 0xFFFF) << 7) + 2 * l);
        unsigned x3 = *(const unsigned*)(hbf + ((size_t)(e3 & 0xFFFF) << 7) + 2 * l);
#define ACC_EDGE(e, x)                                                        \
        {                                                                     \
            int t_ = (e) >> 16;                                               \
            float lo_ = bf2f_u((x) & 0xFFFF), hi_ = bf2f_u((x) >> 16);        \
            if (t_ == 0)      { a00 += lo_; a01 += hi_; c0++; }               \
            else if (t_ == 1) { a10 += lo_; a11 += hi_; c1++; }               \
            else if (t_ == 2) { a20 += lo_; a21 += hi_; c2++; }               \
            else              { a30 += lo_; a31 += hi_; c3++; }               \
        }
        ACC_EDGE(e0, x0) ACC_EDGE(e1, x1) ACC_EDGE(e2, x2) ACC_EDGE(e3, x3)
    }
    for (; i < hi; ++i) {
        int e0 = epack[i];
        unsigned x0 = *(const unsigned*)(hbf + ((size_t)(e0 & 0xFFFF) << 7) + 2 * l);
        ACC_EDGE(e0, x0)
    }
#undef ACC_EDGE
    unsigned* Srow = (unsigned*)(S + (size_t)v * 512);
    Srow[l]       = (unsigned)f2bf(a00) | ((unsigned)f2bf(a01) << 16);
    Srow[64 + l]  = (unsigned)f2bf(a10) | ((unsigned)f2bf(a11) << 16);
    Srow[128 + l] = (unsigned)f2bf(a20) | ((unsigned)f2bf(a21) << 16);
    Srow[192 + l] = (unsigned)f2bf(a30) | ((unsigned)f2bf(a31) << 16);
    if (l == 0) {
        uint4v dg = {c0, c1, c2, c3};
        *(uint4v*)(deg4 + (size_t)v * 4) = dg;
    }
}

// ---------------- a-GEMM: abf[v] = bf16(S[v] @ Wstack + sum_t deg_t(v)*bmsg[t]) --
// block 64 rows (4 waves x 16); K=512; 4 passes x 2 ntiles, stage 32KB/pass
__global__ __launch_bounds__(256) void k_gemm_a(const unsigned short* __restrict__ S,
                                                const unsigned short* __restrict__ Pmsg,
                                                const unsigned* __restrict__ deg4,
                                                const float* __restrict__ bmsg,
                                                unsigned short* __restrict__ abf) {
    __shared__ unsigned short Bs[32 * 64 * 8];  // 32 KB
    int tid = threadIdx.x, w = tid >> 6, l = tid & 63;
    int base = blockIdx.x * 64 + w * 16;
    int lr = l & 15, kb = l >> 4;
    int arow_i = base + lr;
    if (arow_i >= N_NODES) arow_i = N_NODES - 1;
    const short8* arow = (const short8*)(S + (size_t)arow_i * 512);
    short8 af[16];
#pragma unroll
    for (int kc = 0; kc < 16; ++kc) af[kc] = arow[kc * 4 + kb];
    uint4v dg[4];
#pragma unroll
    for (int j = 0; j < 4; ++j) {
        int row = base + kb * 4 + j;
        if (row >= N_NODES) row = N_NODES - 1;
        dg[j] = *(const uint4v*)(deg4 + (size_t)row * 4);
    }
    for (int p = 0; p < 4; ++p) {
        __syncthreads();
#pragma unroll
        for (int j = 0; j < 8; ++j) {
            int ci = j * 4 + w;               // 0..31
            int ntl = ci >> 4, kc = ci & 15;  // local ntile, k-chunk
            size_t f = (size_t)(p * 2 + ntl) * 16 + kc;
            gload_lds16(Pmsg + (f * 64 + l) * 8, Bs + (size_t)ci * 512);
        }
        __syncthreads();
        f32x4 acc[2] = {};
#pragma unroll
        for (int kc = 0; kc < 16; ++kc) {
            short8 b0 = *(const short8*)(Bs + ((0 * 16 + kc) * 64 + l) * 8);
            short8 b1 = *(const short8*)(Bs + ((1 * 16 + kc) * 64 + l) * 8);
            acc[0] = __builtin_amdgcn_mfma_f32_16x16x32_bf16(af[kc], b0, acc[0], 0, 0, 0);
            acc[1] = __builtin_amdgcn_mfma_f32_16x16x32_bf16(af[kc], b1, acc[1], 0, 0, 0);
        }
#pragma unroll
        for (int ntl = 0; ntl < 2; ++ntl) {
            int col = (p * 2 + ntl) * 16 + lr;
            float b0 = bmsg[col], b1 = bmsg[128 + col], b2 = bmsg[256 + col], b3 = bmsg[384 + col];
#pragma unroll
            for (int j = 0; j < 4; ++j) {
                int row = base + kb * 4 + j;
                if (row < N_NODES) {
                    float bias = (float)dg[j].x * b0 + (float)dg[j].y * b1 +
                                 (float)dg[j].z * b2 + (float)dg[j].w * b3;
                    abf[(size_t)row * D + col] = f2bf(acc[ntl][j] + bias);
                }
            }
        }
    }
}

// ---------------- fused GRU: gi = a@Wih^T, gh = h@Whh^T, gates, h update ----
__global__ __launch_bounds__(256) void k_gru(const unsigned short* __restrict__ abf,
                                             unsigned short* __restrict__ hbf,
                                             float* __restrict__ hf,
                                             const unsigned short* __restrict__ Pih,
                                             const unsigned short* __restrict__ Phh,
                                             const float* __restrict__ bih,
                                             const float* __restrict__ bhh) {
    __shared__ unsigned short Bs[32 * 64 * 8];  // 32 KB: [0..15]=ih frags, [16..31]=hh frags
    int tid = threadIdx.x, w = tid >> 6, l = tid & 63;
    int base = blockIdx.x * 64 + w * 16;
    int lr = l & 15, kb = l >> 4;
    int arow_i = base + lr;
    if (arow_i >= N_NODES) arow_i = N_NODES - 1;
    const short8* arow = (const short8*)(abf + (size_t)arow_i * D);
    const short8* hrow = (const short8*)(hbf + (size_t)arow_i * D);
    short8 afa[4], afh[4];
#pragma unroll
    for (int c = 0; c < 4; ++c) { afa[c] = arow[c * 4 + kb]; afh[c] = hrow[c * 4 + kb]; }
    float rr[8][4], zz[8][4];
    for (int p = 0; p < 3; ++p) {
        for (int hp = 0; hp < 2; ++hp) {
            __syncthreads();
#pragma unroll
            for (int j = 0; j < 8; ++j) {
                int ci = j * 4 + w;  // 0..31
                int fl = ci & 15;    // local frag: (nt_local*4 + c)
                const unsigned short* src = (ci < 16) ? Pih : Phh;
                size_t gfrag = (size_t)((p * 8 + hp * 4) * 4 + fl);
                gload_lds16(src + (gfrag * 64 + l) * 8, Bs + (size_t)ci * 512);
            }
            __syncthreads();
            f32x4 ai[4] = {}, ah[4] = {};
#pragma unroll
            for (int c = 0; c < 4; ++c) {
#pragma unroll
                for (int tl = 0; tl < 4; ++tl) {
                    short8 bi = *(const short8*)(Bs + ((tl * 4 + c) * 64 + l) * 8);
                    ai[tl] = __builtin_amdgcn_mfma_f32_16x16x32_bf16(afa[c], bi, ai[tl], 0, 0, 0);
                    short8 bh = *(const short8*)(Bs + ((16 + tl * 4 + c) * 64 + l) * 8);
                    ah[tl] = __builtin_amdgcn_mfma_f32_16x16x32_bf16(afh[c], bh, ah[tl], 0, 0, 0);
                }
            }
#pragma unroll
            for (int tl = 0; tl < 4; ++tl) {
                int t = hp * 4 + tl;
                int col = p * 128 + t * 16 + lr;
                float bi = bih[col], bh = bhh[col];
#pragma unroll
                for (int j = 0; j < 4; ++j) {
                    float Gi = ai[tl][j] + bi, Gh = ah[tl][j] + bh;
                    if (p == 0)      rr[t][j] = fsigmoid(Gi + Gh);
                    else if (p == 1) zz[t][j] = fsigmoid(Gi + Gh);
                    else {
                        float nn = ftanh(Gi + rr[t][j] * Gh);
                        int row = base + kb * 4 + j;
                        if (row < N_NODES) {
                            int dcol = t * 16 + lr;
                            size_t idx = (size_t)row * D + dcol;
                            float hold = hf[idx];
                            float hn = (1.f - zz[t][j]) * nn + zz[t][j] * hold;
                            hf[idx] = hn;
                            hbf[idx] = f2bf(hn);
                        }
                    }
                }
            }
        }
    }
}

// ---------------- pool phase 1: partial row-sums ----------------
__global__ __launch_bounds__(256) void k_pool1(const float* __restrict__ hf,
                                               const int* __restrict__ counts,
                                               float* __restrict__ partial) {
    __shared__ float tmp[256];
    int g = blockIdx.x / POOL_SPLIT;
    int j = blockIdx.x % POOL_SPLIT;
    int t = threadIdx.x;
    int offset = 0;
    for (int i = 0; i < g; ++i) offset += counts[i];
    int cnt = counts[g];
    int d = t & 127, half = t >> 7;
    float acc = 0.f;
    for (int r = 2 * j + half; r < cnt; r += 2 * POOL_SPLIT)
        acc += hf[(size_t)(offset + r) * D + d];
    tmp[t] = acc;
    __syncthreads();
    if (t < D) partial[(size_t)(g * POOL_SPLIT + j) * D + t] = tmp[t] + tmp[t + 128];
}

// ---------------- pool phase 2: combine + MLP + sigmoid ----------------
__global__ __launch_bounds__(256) void k_pool2(const float* __restrict__ partial,
                                               const int* __restrict__ counts,
                                               const float* __restrict__ W1,
                                               const float* __restrict__ b1,
                                               const float* __restrict__ W2,
                                               const float* __restrict__ b2,
                                               float* __restrict__ out) {
    __shared__ float pooled[D];
    __shared__ float xh[HID];
    int g = blockIdx.x;
    int t = threadIdx.x;
    int cnt = counts[g];
    if (t < D) {
        float s = 0.f;
#pragma unroll
        for (int j = 0; j < POOL_SPLIT; ++j)
            s += partial[(size_t)(g * POOL_SPLIT + j) * D + t];
        pooled[t] = s / (float)cnt;
    }
    __syncthreads();
    float x = b1[t];
    for (int k = 0; k < D; ++k) x += pooled[k] * W1[k * HID + t];
    x = fmaxf(x, 0.f);
    xh[t] = x * W2[t];
    __syncthreads();
    for (int s = 128; s > 0; s >>= 1) {
        if (t < s) xh[t] += xh[t + s];
        __syncthreads();
    }
    if (t == 0) out[g] = 1.f / (1.f + __expf(-(xh[0] + b2[0])));
}

extern "C" void kernel_launch(void* const* d_in, const int* in_sizes, int n_in,
                              void* d_out, int out_size, void* d_ws, size_t ws_size,
                              hipStream_t stream) {
    const float* nf   = (const float*)d_in[0];
    const int* esrc   = (const int*)d_in[1];
    const int* edst   = (const int*)d_in[2];
    const int* etyp   = (const int*)d_in[3];
    const int* counts = (const int*)d_in[4];
    const float* Wmsg = (const float*)d_in[5];
    const float* bmsg = (const float*)d_in[6];   // [4][128] flat == [512] concat
    const float* Wih  = (const float*)d_in[7];
    const float* Whh  = (const float*)d_in[8];
    const float* bih  = (const float*)d_in[9];
    const float* bhh  = (const float*)d_in[10];
    const float* W1   = (const float*)d_in[11];
    const float* b1   = (const float*)d_in[12];
    const float* W2   = (const float*)d_in[13];
    const float* b2   = (const float*)d_in[14];
    float* out = (float*)d_out;

    char* ws = (char*)d_ws;
    size_t off = 0;
    auto alloc = [&](size_t bytes) {
        void* p = ws + off;
        off = (off + bytes + 255) & ~(size_t)255;
        return p;
    };
    float* hf            = (float*)alloc((size_t)N_NODES * D * 4);
    unsigned short* hbf  = (unsigned short*)alloc((size_t)N_NODES * D * 2);
    unsigned short* abf  = (unsigned short*)alloc((size_t)N_NODES * D * 2);
    unsigned short* S    = (unsigned short*)alloc((size_t)N_NODES * 512 * 2);
    unsigned short* Pmsg = (unsigned short*)alloc(128 * 64 * 8 * 2);
    unsigned short* Pih  = (unsigned short*)alloc(24 * 4 * 64 * 8 * 2);
    unsigned short* Phh  = (unsigned short*)alloc(24 * 4 * 64 * 8 * 2);
    int* deg    = (int*)alloc((size_t)N_NODES * 4);
    unsigned* deg4 = (unsigned*)alloc((size_t)N_NODES * 16);
    int* rowptr = (int*)alloc((size_t)(N_NODES + 1) * 4);
    int* cursor = (int*)alloc((size_t)N_NODES * 4);
    int* epack  = (int*)alloc((size_t)N_EDGES * 4);
    float* partial = (float*)alloc((size_t)B_GRAPHS * POOL_SPLIT * D * 4);
    int* bsum = (int*)alloc(SCAN_B * 4);
    int* bpfx = (int*)alloc(SCAN_B * 4);

    hipMemsetAsync(deg, 0, (size_t)N_NODES * 4, stream);
    k_init_h<<<(N_NODES * D) / 256, 256, 0, stream>>>(nf, hf, hbf);
    k_hist<<<N_EDGES / 256, 256, 0, stream>>>(edst, deg);
    k_scan1<<<SCAN_B, 256, 0, stream>>>(deg, bsum);
    k_scan2<<<1, 256, 0, stream>>>(bsum, bpfx, rowptr);
    k_scan3<<<SCAN_B, 256, 0, stream>>>(deg, bpfx, rowptr, cursor);
    k_fill<<<N_EDGES / 256, 256, 0, stream>>>(esrc, edst, etyp, cursor, epack);
    k_pack<<<320, 64, 0, stream>>>(Wmsg, Wih, Whh, Pmsg, Pih, Phh);

    int gru_blocks = (N_NODES + 63) / 64;    // 782
    int agg_blocks = (N_NODES + 3) / 4;      // 12500
    for (int s = 0; s < N_STEPS; ++s) {
        k_aggregate_s<<<agg_blocks, 256, 0, stream>>>(hbf, rowptr, epack, S, deg4);
        k_gemm_a<<<gru_blocks, 256, 0, stream>>>(S, Pmsg, deg4, bmsg, abf);
        k_gru<<<gru_blocks, 256, 0, stream>>>(abf, hbf, hf, Pih, Phh, bih, bhh);
    }
    k_pool1<<<B_GRAPHS * POOL_SPLIT, 256, 0, stream>>>(hf, counts, partial);
    k_pool2<<<B_GRAPHS, 256, 0, stream>>>(partial, counts, W1, b1, W2, b2, out);
}